// Round 3
// baseline (922.874 us; speedup 1.0000x reference)
//
#include <hip/hip_runtime.h>
#include <hip/hip_bf16.h>
#include <math.h>

// Problem constants (fixed by the reference module)
#define BB 8
#define QQ 900
#define EE 256
#define NH 8
#define NL 4
#define NP 4
#define HD 32
#define SS 19560   // sum of H*W over levels

typedef short short8 __attribute__((ext_vector_type(8)));
typedef float f32x4 __attribute__((ext_vector_type(4)));

__device__ __forceinline__ unsigned short f2bf(float f) {
    __hip_bfloat16 h = __float2bfloat16(f);
    return *reinterpret_cast<unsigned short*>(&h);
}

// ---------------------------------------------------------------------------
// Pack W_v (fp32 [256,256] row-major k x n) into bf16 MFMA-B-fragment order:
// Wp[((nt*8 + ks)*64 + ln)*8 + j] = bf16(W[ks*32 + (ln>>4)*8 + j][nt*16 + (ln&15)])
// 8192 fragments of 8 shorts = 128 KB.
// ---------------------------------------------------------------------------
__global__ __launch_bounds__(256) void pack_w(
    const float* __restrict__ W, unsigned short* __restrict__ Wp)
{
    const int idx = blockIdx.x * 256 + threadIdx.x;   // 0..8191
    const int nt = idx >> 9;
    const int ks = (idx >> 6) & 7;
    const int ln = idx & 63;
    const int n  = nt * 16 + (ln & 15);
    const int k0 = ks * 32 + (ln >> 4) * 8;
    unsigned short tmp[8];
#pragma unroll
    for (int j = 0; j < 8; ++j)
        tmp[j] = f2bf(W[(size_t)(k0 + j) * 256 + n]);
    *(short8*)(Wp + (size_t)idx * 8) = *(const short8*)tmp;
}

// ---------------------------------------------------------------------------
// Value projection: per block 128 rows x all 256 cols.
// A (fp32) staged in LDS as bf16 per 32-k slice; B fragments from packed Wp
// (L1/L2-resident). Output bf16 in head-major layout [B][NH][S][HD].
// ---------------------------------------------------------------------------
#define GM 128

__global__ __launch_bounds__(256, 2) void gemm_v_bf16(
    const float* __restrict__ A, const unsigned short* __restrict__ Wp,
    const float* __restrict__ bias, unsigned short* __restrict__ C, int M)
{
    __shared__ short As[GM][40];    // 80 B row stride = 5*16B -> conflict-free b128

    const int t = threadIdx.x;
    const int row0 = blockIdx.x * GM;

    const int w = t >> 6;         // wave 0..3 -> rows w*32..w*32+31
    const int ln = t & 63;
    const int quad = ln >> 4;
    const int m16 = ln & 15;

    const int rowa = t >> 1;      // staging: 2 threads/row, 16 floats each
    const int kg = t & 1;

    f32x4 acc[2][16] = {};

    for (int ks = 0; ks < 8; ++ks) {
        const int k0 = ks * 32;
        // ---- stage A k-slice (fp32 -> bf16) ----
        {
            const int grow = row0 + rowa;
            float4 v0 = make_float4(0.f,0.f,0.f,0.f), v1 = v0, v2 = v0, v3 = v0;
            if (grow < M) {
                const float* p = A + (size_t)grow * 256 + k0 + kg * 16;
                v0 = *(const float4*)p;
                v1 = *(const float4*)(p + 4);
                v2 = *(const float4*)(p + 8);
                v3 = *(const float4*)(p + 12);
            }
            unsigned short tmp[16];
            tmp[0]=f2bf(v0.x); tmp[1]=f2bf(v0.y); tmp[2]=f2bf(v0.z); tmp[3]=f2bf(v0.w);
            tmp[4]=f2bf(v1.x); tmp[5]=f2bf(v1.y); tmp[6]=f2bf(v1.z); tmp[7]=f2bf(v1.w);
            tmp[8]=f2bf(v2.x); tmp[9]=f2bf(v2.y); tmp[10]=f2bf(v2.z); tmp[11]=f2bf(v2.w);
            tmp[12]=f2bf(v3.x); tmp[13]=f2bf(v3.y); tmp[14]=f2bf(v3.z); tmp[15]=f2bf(v3.w);
            *(short8*)&As[rowa][kg * 16]     = *(const short8*)&tmp[0];
            *(short8*)&As[rowa][kg * 16 + 8] = *(const short8*)&tmp[8];
        }
        __syncthreads();

        const short8 af0 = *(const short8*)&As[w * 32 + m16][quad * 8];
        const short8 af1 = *(const short8*)&As[w * 32 + 16 + m16][quad * 8];
#pragma unroll 4
        for (int nt = 0; nt < 16; ++nt) {
            const short8 bf = *(const short8*)(Wp + ((size_t)(nt * 8 + ks) * 64 + ln) * 8);
            acc[0][nt] = __builtin_amdgcn_mfma_f32_16x16x32_bf16(af0, bf, acc[0][nt], 0, 0, 0);
            acc[1][nt] = __builtin_amdgcn_mfma_f32_16x16x32_bf16(af1, bf, acc[1][nt], 0, 0, 0);
        }
        __syncthreads();
    }

    // ---- epilogue: + bias, store bf16 head-major [B][NH][S][HD] ----
#pragma unroll
    for (int mt = 0; mt < 2; ++mt) {
#pragma unroll
        for (int r = 0; r < 4; ++r) {
            const int grow = row0 + w * 32 + mt * 16 + quad * 4 + r;
            if (grow >= M) continue;
            const int b = grow / SS;
            const int s = grow - b * SS;
            unsigned short* crow = C + ((size_t)b * 8 * SS + s) * 32;
#pragma unroll
            for (int nt = 0; nt < 16; ++nt) {
                const int col = nt * 16 + m16;
                const float o = acc[mt][nt][r] + bias[col];
                crow[(size_t)(nt >> 1) * SS * 32 + (nt & 1) * 16 + m16] = f2bf(o);
            }
        }
    }
}

// ---------------------------------------------------------------------------
// Generic fp32 tiled GEMM (small GEMMs): C = A@B + bias (+ res)
// ---------------------------------------------------------------------------
#define BM 64
#define BN 64
#define BK 16

__global__ __launch_bounds__(256) void gemm_bias_res(
    const float* __restrict__ A, const float* __restrict__ Bm,
    const float* __restrict__ bias, const float* __restrict__ res,
    float* __restrict__ C, int M, int N, int K)
{
    __shared__ __align__(16) float As[BK][BM + 4];
    __shared__ __align__(16) float Bs[BK][BN + 4];

    const int t = threadIdx.x;
    const int row0 = blockIdx.y * BM;
    const int col0 = blockIdx.x * BN;
    const int tx = t & 15;
    const int ty = t >> 4;
    const int ar = t >> 2;
    const int ak = (t & 3) * 4;
    const int br = t >> 4;
    const int bc = (t & 15) * 4;

    float acc[4][4] = {};

    for (int k0 = 0; k0 < K; k0 += BK) {
        const int arow = row0 + ar;
        float4 av = make_float4(0.f, 0.f, 0.f, 0.f);
        if (arow < M)
            av = *(const float4*)(A + (size_t)arow * K + (k0 + ak));
        As[ak + 0][ar] = av.x;
        As[ak + 1][ar] = av.y;
        As[ak + 2][ar] = av.z;
        As[ak + 3][ar] = av.w;
        *(float4*)&Bs[br][bc] = *(const float4*)(Bm + (size_t)(k0 + br) * N + (col0 + bc));
        __syncthreads();
#pragma unroll
        for (int k = 0; k < BK; ++k) {
            const float4 a = *(const float4*)&As[k][ty * 4];
            const float4 b = *(const float4*)&Bs[k][tx * 4];
            acc[0][0] = fmaf(a.x, b.x, acc[0][0]);
            acc[0][1] = fmaf(a.x, b.y, acc[0][1]);
            acc[0][2] = fmaf(a.x, b.z, acc[0][2]);
            acc[0][3] = fmaf(a.x, b.w, acc[0][3]);
            acc[1][0] = fmaf(a.y, b.x, acc[1][0]);
            acc[1][1] = fmaf(a.y, b.y, acc[1][1]);
            acc[1][2] = fmaf(a.y, b.z, acc[1][2]);
            acc[1][3] = fmaf(a.y, b.w, acc[1][3]);
            acc[2][0] = fmaf(a.z, b.x, acc[2][0]);
            acc[2][1] = fmaf(a.z, b.y, acc[2][1]);
            acc[2][2] = fmaf(a.z, b.z, acc[2][2]);
            acc[2][3] = fmaf(a.z, b.w, acc[2][3]);
            acc[3][0] = fmaf(a.w, b.x, acc[3][0]);
            acc[3][1] = fmaf(a.w, b.y, acc[3][1]);
            acc[3][2] = fmaf(a.w, b.z, acc[3][2]);
            acc[3][3] = fmaf(a.w, b.w, acc[3][3]);
        }
        __syncthreads();
    }

    const int cbase = col0 + tx * 4;
    const float4 bset = *(const float4*)(bias + cbase);
#pragma unroll
    for (int i = 0; i < 4; ++i) {
        const int r = row0 + ty * 4 + i;
        if (r >= M) continue;
        float4 o;
        o.x = acc[i][0] + bset.x;
        o.y = acc[i][1] + bset.y;
        o.z = acc[i][2] + bset.z;
        o.w = acc[i][3] + bset.w;
        if (res) {
            const float4 rv = *(const float4*)(res + (size_t)r * N + cbase);
            o.x += rv.x; o.y += rv.y; o.z += rv.z; o.w += rv.w;
        }
        *(float4*)(C + (size_t)r * N + cbase) = o;
    }
}

// ---------------------------------------------------------------------------
// Sampling: v bf16 head-major [B][NH][S][HD]. 256 threads = 2 queries,
// each query: 8 heads x 16 lanes, 2 channels/lane.
// ---------------------------------------------------------------------------
__global__ __launch_bounds__(256) void msda_sample_bf16(
    const unsigned short* __restrict__ v,  // [B][NH][S][HD] bf16
    const float* __restrict__ off,         // [B*Q, 256]
    const float* __restrict__ logits,      // [B*Q, 128]
    const float* __restrict__ refp,        // [B*Q, 8]
    float* __restrict__ out)               // [B*Q, 256]
{
    const int t = threadIdx.x;       // 0..255
    const int tq = t >> 7;           // query within block
    const int tt = t & 127;
    const int bq = blockIdx.x * 2 + tq;
    const int b = bq / QQ;
    const int h = tt >> 4;           // head 0..7
    const int d2 = tt & 15;          // channel-pair 0..15

    __shared__ float s_off[2][256];
    __shared__ float s_log[2][128];
    __shared__ float s_w[2][128];
    __shared__ float s_ref[2][8];

    *(float2*)&s_off[tq][tt * 2] = *(const float2*)(off + (size_t)bq * 256 + tt * 2);
    const float lg = logits[(size_t)bq * 128 + tt];
    s_log[tq][tt] = lg;
    if (tt < 8) s_ref[tq][tt] = refp[(size_t)bq * 8 + tt];
    __syncthreads();

    {
        const float* l = &s_log[tq][h * 16];
        float m = l[0];
#pragma unroll
        for (int i = 1; i < 16; ++i) m = fmaxf(m, l[i]);
        float ssum = 0.f;
#pragma unroll
        for (int i = 0; i < 16; ++i) ssum += __expf(l[i] - m);
        s_w[tq][tt] = __expf(lg - m) / ssum;
    }
    __syncthreads();

    const int Hs[NL] = {92, 46, 23, 12};
    const int Ws[NL] = {160, 80, 40, 20};
    const int St[NL] = {0, 14720, 18400, 19320};

    // base ptr for this (b, head, channel-pair); row stride 32 bf16 = 64 B
    const unsigned short* vb = v + ((size_t)b * NH + h) * SS * 32 + d2 * 2;

    float ax = 0.f, ay = 0.f;
#pragma unroll
    for (int l = 0; l < NL; ++l) {
        const int Hl = Hs[l], Wl = Ws[l], st = St[l];
        const float rx = s_ref[tq][l * 2 + 0];
        const float ry = s_ref[tq][l * 2 + 1];
#pragma unroll
        for (int p = 0; p < NP; ++p) {
            const float ox = s_off[tq][h * 32 + l * 8 + p * 2 + 0];
            const float oy = s_off[tq][h * 32 + l * 8 + p * 2 + 1];
            const float x = fmaf(rx, (float)Wl, ox) - 0.5f;
            const float y = fmaf(ry, (float)Hl, oy) - 0.5f;
            const float xf = floorf(x);
            const float yf = floorf(y);
            const int x0 = (int)xf;
            const int y0 = (int)yf;
            const float wx = x - xf;
            const float wy = y - yf;
            const float wt = s_w[tq][h * 16 + l * 4 + p];

            const float w00 = wt * (1.f - wy) * (1.f - wx);
            const float w01 = wt * (1.f - wy) * wx;
            const float w10 = wt * wy * (1.f - wx);
            const float w11 = wt * wy * wx;

            const bool vy0 = (y0 >= 0) & (y0 < Hl);
            const bool vy1 = (y0 + 1 >= 0) & (y0 + 1 < Hl);
            const bool vx0 = (x0 >= 0) & (x0 < Wl);
            const bool vx1 = (x0 + 1 >= 0) & (x0 + 1 < Wl);

            if (vy0 & vx0) {
                const unsigned int u = *(const unsigned int*)(vb + (size_t)(st + y0 * Wl + x0) * 32);
                ax = fmaf(w00, __uint_as_float(u << 16), ax);
                ay = fmaf(w00, __uint_as_float(u & 0xffff0000u), ay);
            }
            if (vy0 & vx1) {
                const unsigned int u = *(const unsigned int*)(vb + (size_t)(st + y0 * Wl + x0 + 1) * 32);
                ax = fmaf(w01, __uint_as_float(u << 16), ax);
                ay = fmaf(w01, __uint_as_float(u & 0xffff0000u), ay);
            }
            if (vy1 & vx0) {
                const unsigned int u = *(const unsigned int*)(vb + (size_t)(st + (y0 + 1) * Wl + x0) * 32);
                ax = fmaf(w10, __uint_as_float(u << 16), ax);
                ay = fmaf(w10, __uint_as_float(u & 0xffff0000u), ay);
            }
            if (vy1 & vx1) {
                const unsigned int u = *(const unsigned int*)(vb + (size_t)(st + (y0 + 1) * Wl + x0 + 1) * 32);
                ax = fmaf(w11, __uint_as_float(u << 16), ax);
                ay = fmaf(w11, __uint_as_float(u & 0xffff0000u), ay);
            }
        }
    }
    float2 o; o.x = ax; o.y = ay;
    *(float2*)(out + (size_t)bq * 256 + tt * 2) = o;
}

extern "C" void kernel_launch(void* const* d_in, const int* in_sizes, int n_in,
                              void* d_out, int out_size, void* d_ws, size_t ws_size,
                              hipStream_t stream) {
    const float* query  = (const float*)d_in[0];
    const float* value  = (const float*)d_in[1];
    const float* refp   = (const float*)d_in[2];
    const float* W_off  = (const float*)d_in[4];
    const float* b_off  = (const float*)d_in[5];
    const float* W_attn = (const float*)d_in[6];
    const float* b_attn = (const float*)d_in[7];
    const float* W_v    = (const float*)d_in[8];
    const float* b_v    = (const float*)d_in[9];
    const float* W_out  = (const float*)d_in[10];
    const float* b_out  = (const float*)d_in[11];
    float* out = (float*)d_out;

    // Workspace layout
    unsigned short* v_bf = (unsigned short*)d_ws;                 // B*NH*S*HD bf16 = 80.1 MB
    unsigned short* wp_ws = v_bf + (size_t)BB * SS * 256;         // 65536 bf16 = 128 KB
    float* off_ws  = (float*)(wp_ws + 65536);                     // B*Q*256
    float* log_ws  = off_ws + (size_t)BB * QQ * 256;              // B*Q*128
    float* samp_ws = log_ws + (size_t)BB * QQ * 128;              // B*Q*256

    const int Mv = BB * SS;   // 156480
    const int Mq = BB * QQ;   // 7200

    // 0. pack W_v into bf16 MFMA fragment order
    pack_w<<<dim3(32), dim3(256), 0, stream>>>(W_v, wp_ws);
    // 1. value projection (bf16 MFMA, head-major output)
    gemm_v_bf16<<<dim3((Mv + GM - 1) / GM), dim3(256), 0, stream>>>(
        value, wp_ws, b_v, v_bf, Mv);
    // 2. sampling offsets: off = query @ W_off + b_off
    gemm_bias_res<<<dim3(EE / BN, (Mq + BM - 1) / BM), dim3(256), 0, stream>>>(
        query, W_off, b_off, nullptr, off_ws, Mq, EE, EE);
    // 3. attention logits
    gemm_bias_res<<<dim3(128 / BN, (Mq + BM - 1) / BM), dim3(256), 0, stream>>>(
        query, W_attn, b_attn, nullptr, log_ws, Mq, 128, EE);
    // 4. softmax + bilinear sampling + weighted sum
    msda_sample_bf16<<<dim3(Mq / 2), dim3(256), 0, stream>>>(v_bf, off_ws, log_ws, refp, samp_ws);
    // 5. output projection + residual
    gemm_bias_res<<<dim3(EE / BN, (Mq + BM - 1) / BM), dim3(256), 0, stream>>>(
        samp_ws, W_out, b_out, query, out, Mq, EE, EE);
}

// Round 4
// 900.907 us; speedup vs baseline: 1.0244x; 1.0244x over previous
//
#include <hip/hip_runtime.h>
#include <hip/hip_bf16.h>
#include <math.h>

// Problem constants (fixed by the reference module)
#define BB 8
#define QQ 900
#define EE 256
#define NH 8
#define NL 4
#define NP 4
#define HD 32
#define SS 19560   // sum of H*W over levels

typedef short short8 __attribute__((ext_vector_type(8)));
typedef float f32x4 __attribute__((ext_vector_type(4)));

__device__ __forceinline__ unsigned short f2bf(float f) {
    __hip_bfloat16 h = __float2bfloat16(f);
    return *reinterpret_cast<unsigned short*>(&h);
}

// ---------------------------------------------------------------------------
// Pack W_v (fp32 [256,256] row-major k x n) into bf16 MFMA-B-fragment order:
// Wp[((nt*8 + ks)*64 + ln)*8 + j] = bf16(W[ks*32 + (ln>>4)*8 + j][nt*16 + (ln&15)])
// ---------------------------------------------------------------------------
__global__ __launch_bounds__(256) void pack_w(
    const float* __restrict__ W, unsigned short* __restrict__ Wp)
{
    const int idx = blockIdx.x * 256 + threadIdx.x;   // 0..8191
    const int nt = idx >> 9;
    const int ks = (idx >> 6) & 7;
    const int ln = idx & 63;
    const int n  = nt * 16 + (ln & 15);
    const int k0 = ks * 32 + (ln >> 4) * 8;
    unsigned short tmp[8];
#pragma unroll
    for (int j = 0; j < 8; ++j)
        tmp[j] = f2bf(W[(size_t)(k0 + j) * 256 + n]);
    *(short8*)(Wp + (size_t)idx * 8) = *(const short8*)tmp;
}

// ---------------------------------------------------------------------------
// Value projection: per block 128 rows x all 256 cols. A (fp32) staged in LDS
// as bf16 per 32-k slice; B fragments from packed Wp (L2-resident).
// Output bf16 ROW-MAJOR [M,256] (proven write pattern, R2: WRITE==ideal).
// ---------------------------------------------------------------------------
#define GM 128

__global__ __launch_bounds__(256, 2) void gemm_v_bf16(
    const float* __restrict__ A, const unsigned short* __restrict__ Wp,
    const float* __restrict__ bias, unsigned short* __restrict__ C, int M)
{
    __shared__ short As[GM][40];    // 80 B row stride -> conflict-free b128

    const int t = threadIdx.x;
    const int row0 = blockIdx.x * GM;

    const int w = t >> 6;         // wave 0..3 -> rows w*32..w*32+31
    const int ln = t & 63;
    const int quad = ln >> 4;
    const int m16 = ln & 15;

    const int rowa = t >> 1;      // staging: 2 threads/row, 16 floats each
    const int kg = t & 1;

    f32x4 acc[2][16] = {};

    for (int ks = 0; ks < 8; ++ks) {
        const int k0 = ks * 32;
        // ---- stage A k-slice (fp32 -> bf16) ----
        {
            const int grow = row0 + rowa;
            float4 v0 = make_float4(0.f,0.f,0.f,0.f), v1 = v0, v2 = v0, v3 = v0;
            if (grow < M) {
                const float* p = A + (size_t)grow * 256 + k0 + kg * 16;
                v0 = *(const float4*)p;
                v1 = *(const float4*)(p + 4);
                v2 = *(const float4*)(p + 8);
                v3 = *(const float4*)(p + 12);
            }
            unsigned short tmp[16];
            tmp[0]=f2bf(v0.x); tmp[1]=f2bf(v0.y); tmp[2]=f2bf(v0.z); tmp[3]=f2bf(v0.w);
            tmp[4]=f2bf(v1.x); tmp[5]=f2bf(v1.y); tmp[6]=f2bf(v1.z); tmp[7]=f2bf(v1.w);
            tmp[8]=f2bf(v2.x); tmp[9]=f2bf(v2.y); tmp[10]=f2bf(v2.z); tmp[11]=f2bf(v2.w);
            tmp[12]=f2bf(v3.x); tmp[13]=f2bf(v3.y); tmp[14]=f2bf(v3.z); tmp[15]=f2bf(v3.w);
            *(short8*)&As[rowa][kg * 16]     = *(const short8*)&tmp[0];
            *(short8*)&As[rowa][kg * 16 + 8] = *(const short8*)&tmp[8];
        }
        __syncthreads();

        const short8 af0 = *(const short8*)&As[w * 32 + m16][quad * 8];
        const short8 af1 = *(const short8*)&As[w * 32 + 16 + m16][quad * 8];
#pragma unroll 4
        for (int nt = 0; nt < 16; ++nt) {
            const short8 bf = *(const short8*)(Wp + ((size_t)(nt * 8 + ks) * 64 + ln) * 8);
            acc[0][nt] = __builtin_amdgcn_mfma_f32_16x16x32_bf16(af0, bf, acc[0][nt], 0, 0, 0);
            acc[1][nt] = __builtin_amdgcn_mfma_f32_16x16x32_bf16(af1, bf, acc[1][nt], 0, 0, 0);
        }
        __syncthreads();
    }

    // ---- epilogue: + bias, store bf16 row-major [M,256] ----
    float bset[16];
#pragma unroll
    for (int nt = 0; nt < 16; ++nt) bset[nt] = bias[nt * 16 + m16];

#pragma unroll
    for (int mt = 0; mt < 2; ++mt) {
#pragma unroll
        for (int r = 0; r < 4; ++r) {
            const int row = row0 + w * 32 + mt * 16 + quad * 4 + r;
            if (row >= M) continue;
            unsigned short* crow = C + (size_t)row * 256 + m16;
#pragma unroll
            for (int nt = 0; nt < 16; ++nt)
                crow[nt * 16] = f2bf(acc[mt][nt][r] + bset[nt]);
        }
    }
}

// ---------------------------------------------------------------------------
// Generic fp32 tiled GEMM (small GEMMs): C = A@B + bias (+ res)
// ---------------------------------------------------------------------------
#define BM 64
#define BN 64
#define BK 16

__global__ __launch_bounds__(256) void gemm_bias_res(
    const float* __restrict__ A, const float* __restrict__ Bm,
    const float* __restrict__ bias, const float* __restrict__ res,
    float* __restrict__ C, int M, int N, int K)
{
    __shared__ __align__(16) float As[BK][BM + 4];
    __shared__ __align__(16) float Bs[BK][BN + 4];

    const int t = threadIdx.x;
    const int row0 = blockIdx.y * BM;
    const int col0 = blockIdx.x * BN;
    const int tx = t & 15;
    const int ty = t >> 4;
    const int ar = t >> 2;
    const int ak = (t & 3) * 4;
    const int br = t >> 4;
    const int bc = (t & 15) * 4;

    float acc[4][4] = {};

    for (int k0 = 0; k0 < K; k0 += BK) {
        const int arow = row0 + ar;
        float4 av = make_float4(0.f, 0.f, 0.f, 0.f);
        if (arow < M)
            av = *(const float4*)(A + (size_t)arow * K + (k0 + ak));
        As[ak + 0][ar] = av.x;
        As[ak + 1][ar] = av.y;
        As[ak + 2][ar] = av.z;
        As[ak + 3][ar] = av.w;
        *(float4*)&Bs[br][bc] = *(const float4*)(Bm + (size_t)(k0 + br) * N + (col0 + bc));
        __syncthreads();
#pragma unroll
        for (int k = 0; k < BK; ++k) {
            const float4 a = *(const float4*)&As[k][ty * 4];
            const float4 b = *(const float4*)&Bs[k][tx * 4];
            acc[0][0] = fmaf(a.x, b.x, acc[0][0]);
            acc[0][1] = fmaf(a.x, b.y, acc[0][1]);
            acc[0][2] = fmaf(a.x, b.z, acc[0][2]);
            acc[0][3] = fmaf(a.x, b.w, acc[0][3]);
            acc[1][0] = fmaf(a.y, b.x, acc[1][0]);
            acc[1][1] = fmaf(a.y, b.y, acc[1][1]);
            acc[1][2] = fmaf(a.y, b.z, acc[1][2]);
            acc[1][3] = fmaf(a.y, b.w, acc[1][3]);
            acc[2][0] = fmaf(a.z, b.x, acc[2][0]);
            acc[2][1] = fmaf(a.z, b.y, acc[2][1]);
            acc[2][2] = fmaf(a.z, b.z, acc[2][2]);
            acc[2][3] = fmaf(a.z, b.w, acc[2][3]);
            acc[3][0] = fmaf(a.w, b.x, acc[3][0]);
            acc[3][1] = fmaf(a.w, b.y, acc[3][1]);
            acc[3][2] = fmaf(a.w, b.z, acc[3][2]);
            acc[3][3] = fmaf(a.w, b.w, acc[3][3]);
        }
        __syncthreads();
    }

    const int cbase = col0 + tx * 4;
    const float4 bset = *(const float4*)(bias + cbase);
#pragma unroll
    for (int i = 0; i < 4; ++i) {
        const int r = row0 + ty * 4 + i;
        if (r >= M) continue;
        float4 o;
        o.x = acc[i][0] + bset.x;
        o.y = acc[i][1] + bset.y;
        o.z = acc[i][2] + bset.z;
        o.w = acc[i][3] + bset.w;
        if (res) {
            const float4 rv = *(const float4*)(res + (size_t)r * N + cbase);
            o.x += rv.x; o.y += rv.y; o.z += rv.z; o.w += rv.w;
        }
        *(float4*)(C + (size_t)r * N + cbase) = o;
    }
}

// ---------------------------------------------------------------------------
// Sampling: v in bf16 [B,S,256], 128 threads = 8 heads x 16 lanes, 2 ch/lane.
// (R2-proven version)
// ---------------------------------------------------------------------------
__global__ __launch_bounds__(128) void msda_sample_bf16(
    const unsigned short* __restrict__ v,  // [B*S, 256] bf16
    const float* __restrict__ off,         // [B*Q, 256]
    const float* __restrict__ logits,      // [B*Q, 128]
    const float* __restrict__ refp,        // [B*Q, 8]
    float* __restrict__ out)               // [B*Q, 256]
{
    const int bq = blockIdx.x;
    const int b = bq / QQ;
    const int t = threadIdx.x;   // 0..127
    const int h = t >> 4;        // head 0..7
    const int d2 = t & 15;       // channel-pair 0..15

    __shared__ float s_off[256];
    __shared__ float s_log[128];
    __shared__ float s_w[128];
    __shared__ float s_ref[8];

    *(float2*)&s_off[t * 2] = *(const float2*)(off + (size_t)bq * 256 + t * 2);
    const float lg = logits[(size_t)bq * 128 + t];
    s_log[t] = lg;
    if (t < 8) s_ref[t] = refp[(size_t)bq * 8 + t];
    __syncthreads();

    {
        const float* l = &s_log[h * 16];
        float m = l[0];
#pragma unroll
        for (int i = 1; i < 16; ++i) m = fmaxf(m, l[i]);
        float ssum = 0.f;
#pragma unroll
        for (int i = 0; i < 16; ++i) ssum += __expf(l[i] - m);
        s_w[t] = __expf(lg - m) / ssum;
    }
    __syncthreads();

    const int Hs[NL] = {92, 46, 23, 12};
    const int Ws[NL] = {160, 80, 40, 20};
    const int St[NL] = {0, 14720, 18400, 19320};

    const unsigned short* vb = v + (size_t)b * SS * 256 + h * 32 + d2 * 2;

    float ax = 0.f, ay = 0.f;
#pragma unroll
    for (int l = 0; l < NL; ++l) {
        const int Hl = Hs[l], Wl = Ws[l], st = St[l];
        const float rx = s_ref[l * 2 + 0];
        const float ry = s_ref[l * 2 + 1];
#pragma unroll
        for (int p = 0; p < NP; ++p) {
            const float ox = s_off[h * 32 + l * 8 + p * 2 + 0];
            const float oy = s_off[h * 32 + l * 8 + p * 2 + 1];
            const float x = fmaf(rx, (float)Wl, ox) - 0.5f;
            const float y = fmaf(ry, (float)Hl, oy) - 0.5f;
            const float xf = floorf(x);
            const float yf = floorf(y);
            const int x0 = (int)xf;
            const int y0 = (int)yf;
            const float wx = x - xf;
            const float wy = y - yf;
            const float wt = s_w[h * 16 + l * 4 + p];

            const float w00 = wt * (1.f - wy) * (1.f - wx);
            const float w01 = wt * (1.f - wy) * wx;
            const float w10 = wt * wy * (1.f - wx);
            const float w11 = wt * wy * wx;

            const bool vy0 = (y0 >= 0) & (y0 < Hl);
            const bool vy1 = (y0 + 1 >= 0) & (y0 + 1 < Hl);
            const bool vx0 = (x0 >= 0) & (x0 < Wl);
            const bool vx1 = (x0 + 1 >= 0) & (x0 + 1 < Wl);

            if (vy0 & vx0) {
                const unsigned int u = *(const unsigned int*)(vb + (size_t)(st + y0 * Wl + x0) * 256);
                ax = fmaf(w00, __uint_as_float(u << 16), ax);
                ay = fmaf(w00, __uint_as_float(u & 0xffff0000u), ay);
            }
            if (vy0 & vx1) {
                const unsigned int u = *(const unsigned int*)(vb + (size_t)(st + y0 * Wl + x0 + 1) * 256);
                ax = fmaf(w01, __uint_as_float(u << 16), ax);
                ay = fmaf(w01, __uint_as_float(u & 0xffff0000u), ay);
            }
            if (vy1 & vx0) {
                const unsigned int u = *(const unsigned int*)(vb + (size_t)(st + (y0 + 1) * Wl + x0) * 256);
                ax = fmaf(w10, __uint_as_float(u << 16), ax);
                ay = fmaf(w10, __uint_as_float(u & 0xffff0000u), ay);
            }
            if (vy1 & vx1) {
                const unsigned int u = *(const unsigned int*)(vb + (size_t)(st + (y0 + 1) * Wl + x0 + 1) * 256);
                ax = fmaf(w11, __uint_as_float(u << 16), ax);
                ay = fmaf(w11, __uint_as_float(u & 0xffff0000u), ay);
            }
        }
    }
    float2 o; o.x = ax; o.y = ay;
    *(float2*)(out + (size_t)bq * 256 + t * 2) = o;
}

extern "C" void kernel_launch(void* const* d_in, const int* in_sizes, int n_in,
                              void* d_out, int out_size, void* d_ws, size_t ws_size,
                              hipStream_t stream) {
    const float* query  = (const float*)d_in[0];
    const float* value  = (const float*)d_in[1];
    const float* refp   = (const float*)d_in[2];
    const float* W_off  = (const float*)d_in[4];
    const float* b_off  = (const float*)d_in[5];
    const float* W_attn = (const float*)d_in[6];
    const float* b_attn = (const float*)d_in[7];
    const float* W_v    = (const float*)d_in[8];
    const float* b_v    = (const float*)d_in[9];
    const float* W_out  = (const float*)d_in[10];
    const float* b_out  = (const float*)d_in[11];
    float* out = (float*)d_out;

    // Workspace layout
    unsigned short* v_bf = (unsigned short*)d_ws;                 // B*S*256 bf16 = 80.1 MB
    unsigned short* wp_ws = v_bf + (size_t)BB * SS * 256;         // 65536 bf16 = 128 KB
    float* off_ws  = (float*)(wp_ws + 65536);                     // B*Q*256
    float* log_ws  = off_ws + (size_t)BB * QQ * 256;              // B*Q*128
    float* samp_ws = log_ws + (size_t)BB * QQ * 128;              // B*Q*256

    const int Mv = BB * SS;   // 156480
    const int Mq = BB * QQ;   // 7200

    // 0. pack W_v into bf16 MFMA fragment order
    pack_w<<<dim3(32), dim3(256), 0, stream>>>(W_v, wp_ws);
    // 1. value projection (bf16 MFMA, row-major output)
    gemm_v_bf16<<<dim3((Mv + GM - 1) / GM), dim3(256), 0, stream>>>(
        value, wp_ws, b_v, v_bf, Mv);
    // 2. sampling offsets: off = query @ W_off + b_off
    gemm_bias_res<<<dim3(EE / BN, (Mq + BM - 1) / BM), dim3(256), 0, stream>>>(
        query, W_off, b_off, nullptr, off_ws, Mq, EE, EE);
    // 3. attention logits
    gemm_bias_res<<<dim3(128 / BN, (Mq + BM - 1) / BM), dim3(256), 0, stream>>>(
        query, W_attn, b_attn, nullptr, log_ws, Mq, 128, EE);
    // 4. softmax + bilinear sampling + weighted sum
    msda_sample_bf16<<<dim3(Mq), dim3(128), 0, stream>>>(v_bf, off_ws, log_ws, refp, samp_ws);
    // 5. output projection + residual
    gemm_bias_res<<<dim3(EE / BN, (Mq + BM - 1) / BM), dim3(256), 0, stream>>>(
        samp_ws, W_out, b_out, query, out, Mq, EE, EE);
}

// Round 5
// 399.877 us; speedup vs baseline: 2.3079x; 2.2530x over previous
//
#include <hip/hip_runtime.h>
#include <hip/hip_bf16.h>
#include <math.h>

// Problem constants (fixed by the reference module)
#define BB 8
#define QQ 900
#define EE 256
#define NH 8
#define NL 4
#define NP 4
#define HD 32
#define SS 19560   // sum of H*W over levels

typedef short short8 __attribute__((ext_vector_type(8)));
typedef float f32x4 __attribute__((ext_vector_type(4)));

__device__ __forceinline__ unsigned short f2bf(float f) {
    __hip_bfloat16 h = __float2bfloat16(f);
    return *reinterpret_cast<unsigned short*>(&h);
}

// ---------------------------------------------------------------------------
// Pack W_v (fp32 [256,256] row-major k x n) into bf16 MFMA-B-fragment order:
// Wp[((nt*8 + ks)*64 + ln)*8 + j] = bf16(W[ks*32 + (ln>>4)*8 + j][nt*16 + (ln&15)])
// ---------------------------------------------------------------------------
__global__ __launch_bounds__(256) void pack_w(
    const float* __restrict__ W, unsigned short* __restrict__ Wp)
{
    const int idx = blockIdx.x * 256 + threadIdx.x;   // 0..8191
    const int nt = idx >> 9;
    const int ks = (idx >> 6) & 7;
    const int ln = idx & 63;
    const int n  = nt * 16 + (ln & 15);
    const int k0 = ks * 32 + (ln >> 4) * 8;
    unsigned short tmp[8];
#pragma unroll
    for (int j = 0; j < 8; ++j)
        tmp[j] = f2bf(W[(size_t)(k0 + j) * 256 + n]);
    *(short8*)(Wp + (size_t)idx * 8) = *(const short8*)tmp;
}

// ---------------------------------------------------------------------------
// Value projection: per block 128 rows x all 256 cols. A (fp32) staged in LDS
// as bf16 per 32-k slice; B fragments from packed Wp (L2-resident).
// Output bf16 row-major [M,256].
// CRITICAL: nt loop is FULLY unrolled -> acc[][] statically indexed -> stays
// in registers. (R3/R4 regression: "#pragma unroll 4" left nt dynamic, the
// 128-reg acc array was demoted to scratch -> 2.3 GB of scratch HBM traffic,
// VGPR_Count=32, MfmaUtil 1.3%.)
// ---------------------------------------------------------------------------
#define GM 128

__global__ __launch_bounds__(256, 2) void gemm_v_bf16(
    const float* __restrict__ A, const unsigned short* __restrict__ Wp,
    const float* __restrict__ bias, unsigned short* __restrict__ C, int M)
{
    __shared__ short As[GM][40];    // 80 B row stride -> conflict-free b128

    const int t = threadIdx.x;
    const int row0 = blockIdx.x * GM;

    const int w = t >> 6;         // wave 0..3 -> rows w*32..w*32+31
    const int ln = t & 63;
    const int quad = ln >> 4;
    const int m16 = ln & 15;

    const int rowa = t >> 1;      // staging: 2 threads/row, 16 floats each
    const int kg = t & 1;

    f32x4 acc[2][16] = {};

    for (int ks = 0; ks < 8; ++ks) {
        const int k0 = ks * 32;
        // ---- stage A k-slice (fp32 -> bf16) ----
        {
            const int grow = row0 + rowa;
            float4 v0 = make_float4(0.f,0.f,0.f,0.f), v1 = v0, v2 = v0, v3 = v0;
            if (grow < M) {
                const float* p = A + (size_t)grow * 256 + k0 + kg * 16;
                v0 = *(const float4*)p;
                v1 = *(const float4*)(p + 4);
                v2 = *(const float4*)(p + 8);
                v3 = *(const float4*)(p + 12);
            }
            unsigned short tmp[16];
            tmp[0]=f2bf(v0.x); tmp[1]=f2bf(v0.y); tmp[2]=f2bf(v0.z); tmp[3]=f2bf(v0.w);
            tmp[4]=f2bf(v1.x); tmp[5]=f2bf(v1.y); tmp[6]=f2bf(v1.z); tmp[7]=f2bf(v1.w);
            tmp[8]=f2bf(v2.x); tmp[9]=f2bf(v2.y); tmp[10]=f2bf(v2.z); tmp[11]=f2bf(v2.w);
            tmp[12]=f2bf(v3.x); tmp[13]=f2bf(v3.y); tmp[14]=f2bf(v3.z); tmp[15]=f2bf(v3.w);
            *(short8*)&As[rowa][kg * 16]     = *(const short8*)&tmp[0];
            *(short8*)&As[rowa][kg * 16 + 8] = *(const short8*)&tmp[8];
        }
        __syncthreads();

        const short8 af0 = *(const short8*)&As[w * 32 + m16][quad * 8];
        const short8 af1 = *(const short8*)&As[w * 32 + 16 + m16][quad * 8];
#pragma unroll
        for (int nt = 0; nt < 16; ++nt) {
            const short8 bf = *(const short8*)(Wp + ((size_t)(nt * 8 + ks) * 64 + ln) * 8);
            acc[0][nt] = __builtin_amdgcn_mfma_f32_16x16x32_bf16(af0, bf, acc[0][nt], 0, 0, 0);
            acc[1][nt] = __builtin_amdgcn_mfma_f32_16x16x32_bf16(af1, bf, acc[1][nt], 0, 0, 0);
        }
        __syncthreads();
    }

    // ---- epilogue: + bias, store bf16 row-major [M,256] ----
    float bset[16];
#pragma unroll
    for (int nt = 0; nt < 16; ++nt) bset[nt] = bias[nt * 16 + m16];

#pragma unroll
    for (int mt = 0; mt < 2; ++mt) {
#pragma unroll
        for (int r = 0; r < 4; ++r) {
            const int row = row0 + w * 32 + mt * 16 + quad * 4 + r;
            if (row >= M) continue;
            unsigned short* crow = C + (size_t)row * 256 + m16;
#pragma unroll
            for (int nt = 0; nt < 16; ++nt)
                crow[nt * 16] = f2bf(acc[mt][nt][r] + bset[nt]);
        }
    }
}

// ---------------------------------------------------------------------------
// Generic fp32 tiled GEMM (small GEMMs): C = A@B + bias (+ res)
// ---------------------------------------------------------------------------
#define BM 64
#define BN 64
#define BK 16

__global__ __launch_bounds__(256) void gemm_bias_res(
    const float* __restrict__ A, const float* __restrict__ Bm,
    const float* __restrict__ bias, const float* __restrict__ res,
    float* __restrict__ C, int M, int N, int K)
{
    __shared__ __align__(16) float As[BK][BM + 4];
    __shared__ __align__(16) float Bs[BK][BN + 4];

    const int t = threadIdx.x;
    const int row0 = blockIdx.y * BM;
    const int col0 = blockIdx.x * BN;
    const int tx = t & 15;
    const int ty = t >> 4;
    const int ar = t >> 2;
    const int ak = (t & 3) * 4;
    const int br = t >> 4;
    const int bc = (t & 15) * 4;

    float acc[4][4] = {};

    for (int k0 = 0; k0 < K; k0 += BK) {
        const int arow = row0 + ar;
        float4 av = make_float4(0.f, 0.f, 0.f, 0.f);
        if (arow < M)
            av = *(const float4*)(A + (size_t)arow * K + (k0 + ak));
        As[ak + 0][ar] = av.x;
        As[ak + 1][ar] = av.y;
        As[ak + 2][ar] = av.z;
        As[ak + 3][ar] = av.w;
        *(float4*)&Bs[br][bc] = *(const float4*)(Bm + (size_t)(k0 + br) * N + (col0 + bc));
        __syncthreads();
#pragma unroll
        for (int k = 0; k < BK; ++k) {
            const float4 a = *(const float4*)&As[k][ty * 4];
            const float4 b = *(const float4*)&Bs[k][tx * 4];
            acc[0][0] = fmaf(a.x, b.x, acc[0][0]);
            acc[0][1] = fmaf(a.x, b.y, acc[0][1]);
            acc[0][2] = fmaf(a.x, b.z, acc[0][2]);
            acc[0][3] = fmaf(a.x, b.w, acc[0][3]);
            acc[1][0] = fmaf(a.y, b.x, acc[1][0]);
            acc[1][1] = fmaf(a.y, b.y, acc[1][1]);
            acc[1][2] = fmaf(a.y, b.z, acc[1][2]);
            acc[1][3] = fmaf(a.y, b.w, acc[1][3]);
            acc[2][0] = fmaf(a.z, b.x, acc[2][0]);
            acc[2][1] = fmaf(a.z, b.y, acc[2][1]);
            acc[2][2] = fmaf(a.z, b.z, acc[2][2]);
            acc[2][3] = fmaf(a.z, b.w, acc[2][3]);
            acc[3][0] = fmaf(a.w, b.x, acc[3][0]);
            acc[3][1] = fmaf(a.w, b.y, acc[3][1]);
            acc[3][2] = fmaf(a.w, b.z, acc[3][2]);
            acc[3][3] = fmaf(a.w, b.w, acc[3][3]);
        }
        __syncthreads();
    }

    const int cbase = col0 + tx * 4;
    const float4 bset = *(const float4*)(bias + cbase);
#pragma unroll
    for (int i = 0; i < 4; ++i) {
        const int r = row0 + ty * 4 + i;
        if (r >= M) continue;
        float4 o;
        o.x = acc[i][0] + bset.x;
        o.y = acc[i][1] + bset.y;
        o.z = acc[i][2] + bset.z;
        o.w = acc[i][3] + bset.w;
        if (res) {
            const float4 rv = *(const float4*)(res + (size_t)r * N + cbase);
            o.x += rv.x; o.y += rv.y; o.z += rv.z; o.w += rv.w;
        }
        *(float4*)(C + (size_t)r * N + cbase) = o;
    }
}

// ---------------------------------------------------------------------------
// Sampling: v in bf16 [B,S,256], 128 threads = 8 heads x 16 lanes, 2 ch/lane.
// (R2-proven version)
// ---------------------------------------------------------------------------
__global__ __launch_bounds__(128) void msda_sample_bf16(
    const unsigned short* __restrict__ v,  // [B*S, 256] bf16
    const float* __restrict__ off,         // [B*Q, 256]
    const float* __restrict__ logits,      // [B*Q, 128]
    const float* __restrict__ refp,        // [B*Q, 8]
    float* __restrict__ out)               // [B*Q, 256]
{
    const int bq = blockIdx.x;
    const int b = bq / QQ;
    const int t = threadIdx.x;   // 0..127
    const int h = t >> 4;        // head 0..7
    const int d2 = t & 15;       // channel-pair 0..15

    __shared__ float s_off[256];
    __shared__ float s_log[128];
    __shared__ float s_w[128];
    __shared__ float s_ref[8];

    *(float2*)&s_off[t * 2] = *(const float2*)(off + (size_t)bq * 256 + t * 2);
    const float lg = logits[(size_t)bq * 128 + t];
    s_log[t] = lg;
    if (t < 8) s_ref[t] = refp[(size_t)bq * 8 + t];
    __syncthreads();

    {
        const float* l = &s_log[h * 16];
        float m = l[0];
#pragma unroll
        for (int i = 1; i < 16; ++i) m = fmaxf(m, l[i]);
        float ssum = 0.f;
#pragma unroll
        for (int i = 0; i < 16; ++i) ssum += __expf(l[i] - m);
        s_w[t] = __expf(lg - m) / ssum;
    }
    __syncthreads();

    const int Hs[NL] = {92, 46, 23, 12};
    const int Ws[NL] = {160, 80, 40, 20};
    const int St[NL] = {0, 14720, 18400, 19320};

    const unsigned short* vb = v + (size_t)b * SS * 256 + h * 32 + d2 * 2;

    float ax = 0.f, ay = 0.f;
#pragma unroll
    for (int l = 0; l < NL; ++l) {
        const int Hl = Hs[l], Wl = Ws[l], st = St[l];
        const float rx = s_ref[l * 2 + 0];
        const float ry = s_ref[l * 2 + 1];
#pragma unroll
        for (int p = 0; p < NP; ++p) {
            const float ox = s_off[h * 32 + l * 8 + p * 2 + 0];
            const float oy = s_off[h * 32 + l * 8 + p * 2 + 1];
            const float x = fmaf(rx, (float)Wl, ox) - 0.5f;
            const float y = fmaf(ry, (float)Hl, oy) - 0.5f;
            const float xf = floorf(x);
            const float yf = floorf(y);
            const int x0 = (int)xf;
            const int y0 = (int)yf;
            const float wx = x - xf;
            const float wy = y - yf;
            const float wt = s_w[h * 16 + l * 4 + p];

            const float w00 = wt * (1.f - wy) * (1.f - wx);
            const float w01 = wt * (1.f - wy) * wx;
            const float w10 = wt * wy * (1.f - wx);
            const float w11 = wt * wy * wx;

            const bool vy0 = (y0 >= 0) & (y0 < Hl);
            const bool vy1 = (y0 + 1 >= 0) & (y0 + 1 < Hl);
            const bool vx0 = (x0 >= 0) & (x0 < Wl);
            const bool vx1 = (x0 + 1 >= 0) & (x0 + 1 < Wl);

            if (vy0 & vx0) {
                const unsigned int u = *(const unsigned int*)(vb + (size_t)(st + y0 * Wl + x0) * 256);
                ax = fmaf(w00, __uint_as_float(u << 16), ax);
                ay = fmaf(w00, __uint_as_float(u & 0xffff0000u), ay);
            }
            if (vy0 & vx1) {
                const unsigned int u = *(const unsigned int*)(vb + (size_t)(st + y0 * Wl + x0 + 1) * 256);
                ax = fmaf(w01, __uint_as_float(u << 16), ax);
                ay = fmaf(w01, __uint_as_float(u & 0xffff0000u), ay);
            }
            if (vy1 & vx0) {
                const unsigned int u = *(const unsigned int*)(vb + (size_t)(st + (y0 + 1) * Wl + x0) * 256);
                ax = fmaf(w10, __uint_as_float(u << 16), ax);
                ay = fmaf(w10, __uint_as_float(u & 0xffff0000u), ay);
            }
            if (vy1 & vx1) {
                const unsigned int u = *(const unsigned int*)(vb + (size_t)(st + (y0 + 1) * Wl + x0 + 1) * 256);
                ax = fmaf(w11, __uint_as_float(u << 16), ax);
                ay = fmaf(w11, __uint_as_float(u & 0xffff0000u), ay);
            }
        }
    }
    float2 o; o.x = ax; o.y = ay;
    *(float2*)(out + (size_t)bq * 256 + t * 2) = o;
}

extern "C" void kernel_launch(void* const* d_in, const int* in_sizes, int n_in,
                              void* d_out, int out_size, void* d_ws, size_t ws_size,
                              hipStream_t stream) {
    const float* query  = (const float*)d_in[0];
    const float* value  = (const float*)d_in[1];
    const float* refp   = (const float*)d_in[2];
    const float* W_off  = (const float*)d_in[4];
    const float* b_off  = (const float*)d_in[5];
    const float* W_attn = (const float*)d_in[6];
    const float* b_attn = (const float*)d_in[7];
    const float* W_v    = (const float*)d_in[8];
    const float* b_v    = (const float*)d_in[9];
    const float* W_out  = (const float*)d_in[10];
    const float* b_out  = (const float*)d_in[11];
    float* out = (float*)d_out;

    // Workspace layout
    unsigned short* v_bf = (unsigned short*)d_ws;                 // B*S*256 bf16 = 80.1 MB
    unsigned short* wp_ws = v_bf + (size_t)BB * SS * 256;         // 65536 bf16 = 128 KB
    float* off_ws  = (float*)(wp_ws + 65536);                     // B*Q*256
    float* log_ws  = off_ws + (size_t)BB * QQ * 256;              // B*Q*128
    float* samp_ws = log_ws + (size_t)BB * QQ * 128;              // B*Q*256

    const int Mv = BB * SS;   // 156480
    const int Mq = BB * QQ;   // 7200

    // 0. pack W_v into bf16 MFMA fragment order
    pack_w<<<dim3(32), dim3(256), 0, stream>>>(W_v, wp_ws);
    // 1. value projection (bf16 MFMA, row-major output)
    gemm_v_bf16<<<dim3((Mv + GM - 1) / GM), dim3(256), 0, stream>>>(
        value, wp_ws, b_v, v_bf, Mv);
    // 2. sampling offsets: off = query @ W_off + b_off
    gemm_bias_res<<<dim3(EE / BN, (Mq + BM - 1) / BM), dim3(256), 0, stream>>>(
        query, W_off, b_off, nullptr, off_ws, Mq, EE, EE);
    // 3. attention logits
    gemm_bias_res<<<dim3(128 / BN, (Mq + BM - 1) / BM), dim3(256), 0, stream>>>(
        query, W_attn, b_attn, nullptr, log_ws, Mq, 128, EE);
    // 4. softmax + bilinear sampling + weighted sum
    msda_sample_bf16<<<dim3(Mq), dim3(128), 0, stream>>>(v_bf, off_ws, log_ws, refp, samp_ws);
    // 5. output projection + residual
    gemm_bias_res<<<dim3(EE / BN, (Mq + BM - 1) / BM), dim3(256), 0, stream>>>(
        samp_ws, W_out, b_out, query, out, Mq, EE, EE);
}

// Round 6
// 368.441 us; speedup vs baseline: 2.5048x; 1.0853x over previous
//
#include <hip/hip_runtime.h>
#include <hip/hip_bf16.h>
#include <math.h>

// Problem constants (fixed by the reference module)
#define BB 8
#define QQ 900
#define EE 256
#define NH 8
#define NL 4
#define NP 4
#define HD 32
#define SS 19560   // sum of H*W over levels

typedef short short8 __attribute__((ext_vector_type(8)));
typedef float f32x4 __attribute__((ext_vector_type(4)));

__device__ __forceinline__ unsigned short f2bf(float f) {
    __hip_bfloat16 h = __float2bfloat16(f);
    return *reinterpret_cast<unsigned short*>(&h);
}

__device__ __forceinline__ short8 cvt8(const float4 a, const float4 b) {
    unsigned short tmp[8];
    tmp[0] = f2bf(a.x); tmp[1] = f2bf(a.y); tmp[2] = f2bf(a.z); tmp[3] = f2bf(a.w);
    tmp[4] = f2bf(b.x); tmp[5] = f2bf(b.y); tmp[6] = f2bf(b.z); tmp[7] = f2bf(b.w);
    return *(const short8*)tmp;
}

// ---------------------------------------------------------------------------
// Pack all weights into bf16 MFMA B-fragment order. Fragment f within a
// region: cb = f>>5 (64-col block), ks = (f>>2)&7 (32-k slice), nt = f&3
// (16-col tile). Lane ln holds B[k = ks*32+(ln>>4)*8+j][col = cb*64+nt*16+(ln&15)].
// Regions: [0..8192) W_v(N=256), [8192..20480) W_off||W_attn (N=384),
// [20480..28672) W_out (N=256). 28672 threads total.
// ---------------------------------------------------------------------------
__global__ __launch_bounds__(256) void pack_all(
    const float* __restrict__ Wv, const float* __restrict__ Woff,
    const float* __restrict__ Wattn, const float* __restrict__ Wout,
    unsigned short* __restrict__ Wp)
{
    const int tid = blockIdx.x * 256 + threadIdx.x;  // 0..28671
    const float* src = Wv;
    int srcN = 256;
    int u = tid;
    if (tid >= 20480)     { u = tid - 20480; src = Wout; srcN = 256; }
    else if (tid >= 8192) { u = tid - 8192; }

    const int f = u >> 6, ln2 = u & 63;
    const int cb = f >> 5, ks = (f >> 2) & 7, nt = f & 3;
    int ncol = cb * 64 + nt * 16 + (ln2 & 15);
    if (tid >= 8192 && tid < 20480) {
        if (ncol < 256) { src = Woff; srcN = 256; }
        else            { src = Wattn; srcN = 128; ncol -= 256; }
    }
    const int k0 = ks * 32 + (ln2 >> 4) * 8;
    unsigned short tmp[8];
#pragma unroll
    for (int j = 0; j < 8; ++j)
        tmp[j] = f2bf(src[(size_t)(k0 + j) * srcN + ncol]);
    *(short8*)(Wp + (size_t)tid * 8) = *(const short8*)tmp;
}

// ---------------------------------------------------------------------------
// Value projection: 128 rows x 256 cols per block, NO LDS, NO barriers.
// A fragments loaded directly from global (wave = 16 rows x 128 B fully-used
// segments, each A row read once per block); B fragments from packed Wp
// (L2-resident). acc[2][16] fully statically indexed (scratch-demotion
// lesson from R3/R4: any dynamic index -> 2.3 GB scratch traffic).
// ---------------------------------------------------------------------------
__global__ __launch_bounds__(256, 2) void gemm_v_bf16(
    const float* __restrict__ A, const unsigned short* __restrict__ Wp,
    const float* __restrict__ bias, unsigned short* __restrict__ C, int M)
{
    const int t = threadIdx.x;
    const int w = t >> 6, ln = t & 63, quad = ln >> 4, m16 = ln & 15;
    const int row0 = blockIdx.x * 128;
    const int r0 = row0 + w * 32 + m16;   // A row for af0
    const int r1 = r0 + 16;               // A row for af1

    f32x4 acc[2][16] = {};

#pragma unroll
    for (int ks = 0; ks < 8; ++ks) {
        short8 af0, af1;
        {
            float4 a0 = make_float4(0.f, 0.f, 0.f, 0.f), a1 = a0;
            if (r0 < M) {
                const float* p = A + (size_t)r0 * 256 + ks * 32 + quad * 8;
                a0 = *(const float4*)p;
                a1 = *(const float4*)(p + 4);
            }
            af0 = cvt8(a0, a1);
        }
        {
            float4 a0 = make_float4(0.f, 0.f, 0.f, 0.f), a1 = a0;
            if (r1 < M) {
                const float* p = A + (size_t)r1 * 256 + ks * 32 + quad * 8;
                a0 = *(const float4*)p;
                a1 = *(const float4*)(p + 4);
            }
            af1 = cvt8(a0, a1);
        }
#pragma unroll
        for (int nt = 0; nt < 16; ++nt) {
            const int fidx = ((nt >> 2) * 8 + ks) * 4 + (nt & 3);
            const short8 bf = *(const short8*)(Wp + ((size_t)fidx * 64 + ln) * 8);
            acc[0][nt] = __builtin_amdgcn_mfma_f32_16x16x32_bf16(af0, bf, acc[0][nt], 0, 0, 0);
            acc[1][nt] = __builtin_amdgcn_mfma_f32_16x16x32_bf16(af1, bf, acc[1][nt], 0, 0, 0);
        }
    }

    // epilogue: + bias, bf16 row-major [M,256] (R2/R5-proven store pattern)
    float bset[16];
#pragma unroll
    for (int nt = 0; nt < 16; ++nt) bset[nt] = bias[(nt >> 2) * 64 + (nt & 3) * 16 + m16];

#pragma unroll
    for (int mt = 0; mt < 2; ++mt) {
#pragma unroll
        for (int r = 0; r < 4; ++r) {
            const int row = row0 + w * 32 + mt * 16 + quad * 4 + r;
            if (row >= M) continue;
            unsigned short* crow = C + (size_t)row * 256 + m16;
#pragma unroll
            for (int nt = 0; nt < 16; ++nt)
                crow[(nt >> 2) * 64 + (nt & 3) * 16] = f2bf(acc[mt][nt][r] + bset[nt]);
        }
    }
}

// ---------------------------------------------------------------------------
// Query-side MFMA GEMM: 64 rows x 64 cols per block, no LDS/barriers.
// C fp32 [M,N] = A fp32 [M,256] @ W + bias (+ res). bias col<split -> bias0
// else bias1[col-split]. Wave w covers rows w*16..+15, acc[4] static.
// ---------------------------------------------------------------------------
__global__ __launch_bounds__(256) void gemm_q(
    const float* __restrict__ A, const unsigned short* __restrict__ Wp,
    const float* __restrict__ bias0, const float* __restrict__ bias1, int split,
    const float* __restrict__ res, float* __restrict__ C, int M, int N)
{
    const int t = threadIdx.x;
    const int w = t >> 6, ln = t & 63, quad = ln >> 4, m16 = ln & 15;
    const int cb = blockIdx.x;
    const int row0 = blockIdx.y * 64;
    const int r0 = row0 + w * 16 + m16;

    f32x4 acc[4] = {};

#pragma unroll
    for (int ks = 0; ks < 8; ++ks) {
        float4 a0 = make_float4(0.f, 0.f, 0.f, 0.f), a1 = a0;
        if (r0 < M) {
            const float* p = A + (size_t)r0 * 256 + ks * 32 + quad * 8;
            a0 = *(const float4*)p;
            a1 = *(const float4*)(p + 4);
        }
        const short8 af = cvt8(a0, a1);
#pragma unroll
        for (int nt = 0; nt < 4; ++nt) {
            const short8 bf = *(const short8*)(Wp + ((size_t)((cb * 8 + ks) * 4 + nt) * 64 + ln) * 8);
            acc[nt] = __builtin_amdgcn_mfma_f32_16x16x32_bf16(af, bf, acc[nt], 0, 0, 0);
        }
    }

#pragma unroll
    for (int nt = 0; nt < 4; ++nt) {
        const int col = cb * 64 + nt * 16 + m16;
        const float bv = (col < split) ? bias0[col] : bias1[col - split];
#pragma unroll
        for (int r = 0; r < 4; ++r) {
            const int row = row0 + w * 16 + quad * 4 + r;
            if (row >= M) continue;
            float o = acc[nt][r] + bv;
            if (res) o += res[(size_t)row * N + col];
            C[(size_t)row * N + col] = o;
        }
    }
}

// ---------------------------------------------------------------------------
// Sampling v2: precompute per-(h,l,p) tuples (clamped addresses + weights
// with validity folded in) in LDS, then a tight unconditional gather loop.
// 256 threads = 2 queries; per query 8 heads x 16 lanes, 2 ch/lane.
// ---------------------------------------------------------------------------
__global__ __launch_bounds__(256) void msda_sample2(
    const unsigned short* __restrict__ v,   // [B*S, 256] bf16
    const float* __restrict__ qcat,         // [B*Q, 384]: off 0..255, logits 256..383
    const float* __restrict__ refp,         // [B*Q, 8]
    float* __restrict__ out)                // [B*Q, 256]
{
    const int t = threadIdx.x;
    const int tq = t >> 7, tt = t & 127;
    const int bq = blockIdx.x * 2 + tq;
    const int b = bq / QQ;

    __shared__ float s_off[2][256];
    __shared__ float s_log[2][128];
    __shared__ float s_ref[2][8];
    __shared__ int   s_adr[2][8][17][4];   // [q][head][lp + pad][corner]
    __shared__ float s_wt [2][8][17][4];

    const float* qrow = qcat + (size_t)bq * 384;
    *(float2*)&s_off[tq][tt * 2] = *(const float2*)(qrow + tt * 2);
    s_log[tq][tt] = qrow[256 + tt];
    if (tt < 8) s_ref[tq][tt] = refp[(size_t)bq * 8 + tt];
    __syncthreads();

    {   // precompute: this thread owns tuple (head hh, level pl, point pp)
        const int hh = tt >> 4, lp = tt & 15, pl = lp >> 2, pp = lp & 3;
        const int Wl = 160 >> pl;
        const int Hl = (pl == 0) ? 92 : (pl == 1) ? 46 : (pl == 2) ? 23 : 12;
        const int st = (pl == 0) ? 0 : (pl == 1) ? 14720 : (pl == 2) ? 18400 : 19320;

        const float* lg = &s_log[tq][hh * 16];
        float m = lg[0];
#pragma unroll
        for (int i = 1; i < 16; ++i) m = fmaxf(m, lg[i]);
        float ssum = 0.f;
#pragma unroll
        for (int i = 0; i < 16; ++i) ssum += __expf(lg[i] - m);
        const float wt = __expf(lg[lp] - m) / ssum;

        const float rx = s_ref[tq][pl * 2 + 0];
        const float ry = s_ref[tq][pl * 2 + 1];
        const float ox = s_off[tq][hh * 32 + pl * 8 + pp * 2 + 0];
        const float oy = s_off[tq][hh * 32 + pl * 8 + pp * 2 + 1];
        const float x = fmaf(rx, (float)Wl, ox) - 0.5f;
        const float y = fmaf(ry, (float)Hl, oy) - 0.5f;
        const float xf = floorf(x), yf = floorf(y);
        const int x0 = (int)xf, y0 = (int)yf;
        const float wx = x - xf, wy = y - yf;

        const float fx0 = (x0 >= 0 && x0 < Wl) ? 1.f : 0.f;
        const float fx1 = (x0 + 1 >= 0 && x0 + 1 < Wl) ? 1.f : 0.f;
        const float fy0 = (y0 >= 0 && y0 < Hl) ? 1.f : 0.f;
        const float fy1 = (y0 + 1 >= 0 && y0 + 1 < Hl) ? 1.f : 0.f;
        const int x0c = min(max(x0, 0), Wl - 1);
        const int x1c = min(max(x0 + 1, 0), Wl - 1);
        const int y0c = min(max(y0, 0), Hl - 1);
        const int y1c = min(max(y0 + 1, 0), Hl - 1);

        s_adr[tq][hh][lp][0] = st + y0c * Wl + x0c;
        s_adr[tq][hh][lp][1] = st + y0c * Wl + x1c;
        s_adr[tq][hh][lp][2] = st + y1c * Wl + x0c;
        s_adr[tq][hh][lp][3] = st + y1c * Wl + x1c;
        s_wt[tq][hh][lp][0] = wt * (1.f - wy) * (1.f - wx) * fy0 * fx0;
        s_wt[tq][hh][lp][1] = wt * (1.f - wy) * wx * fy0 * fx1;
        s_wt[tq][hh][lp][2] = wt * wy * (1.f - wx) * fy1 * fx0;
        s_wt[tq][hh][lp][3] = wt * wy * wx * fy1 * fx1;
    }
    __syncthreads();

    const int hh = tt >> 4, d2 = tt & 15;
    const unsigned short* vb = v + (size_t)b * SS * 256 + hh * 32 + d2 * 2;

    float ax0 = 0.f, ay0 = 0.f, ax1 = 0.f, ay1 = 0.f;
#pragma unroll
    for (int s = 0; s < 16; ++s) {
        const int4   rr = *(const int4*)&s_adr[tq][hh][s][0];
        const float4 ww = *(const float4*)&s_wt[tq][hh][s][0];
        const unsigned int u00 = *(const unsigned int*)(vb + (size_t)rr.x * 256);
        const unsigned int u01 = *(const unsigned int*)(vb + (size_t)rr.y * 256);
        const unsigned int u10 = *(const unsigned int*)(vb + (size_t)rr.z * 256);
        const unsigned int u11 = *(const unsigned int*)(vb + (size_t)rr.w * 256);
        ax0 = fmaf(ww.x, __uint_as_float(u00 << 16), ax0);
        ay0 = fmaf(ww.x, __uint_as_float(u00 & 0xffff0000u), ay0);
        ax0 = fmaf(ww.y, __uint_as_float(u01 << 16), ax0);
        ay0 = fmaf(ww.y, __uint_as_float(u01 & 0xffff0000u), ay0);
        ax1 = fmaf(ww.z, __uint_as_float(u10 << 16), ax1);
        ay1 = fmaf(ww.z, __uint_as_float(u10 & 0xffff0000u), ay1);
        ax1 = fmaf(ww.w, __uint_as_float(u11 << 16), ax1);
        ay1 = fmaf(ww.w, __uint_as_float(u11 & 0xffff0000u), ay1);
    }
    float2 o;
    o.x = ax0 + ax1;
    o.y = ay0 + ay1;
    *(float2*)(out + (size_t)bq * 256 + tt * 2) = o;
}

extern "C" void kernel_launch(void* const* d_in, const int* in_sizes, int n_in,
                              void* d_out, int out_size, void* d_ws, size_t ws_size,
                              hipStream_t stream) {
    const float* query  = (const float*)d_in[0];
    const float* value  = (const float*)d_in[1];
    const float* refp   = (const float*)d_in[2];
    const float* W_off  = (const float*)d_in[4];
    const float* b_off  = (const float*)d_in[5];
    const float* W_attn = (const float*)d_in[6];
    const float* b_attn = (const float*)d_in[7];
    const float* W_v    = (const float*)d_in[8];
    const float* b_v    = (const float*)d_in[9];
    const float* W_out  = (const float*)d_in[10];
    const float* b_out  = (const float*)d_in[11];
    float* out = (float*)d_out;

    // Workspace layout
    unsigned short* v_bf = (unsigned short*)d_ws;                 // B*S*256 bf16 = 80.1 MB
    unsigned short* wp   = v_bf + (size_t)BB * SS * 256;          // 28672*8 bf16 = 448 KB
    unsigned short* wp_v = wp;                                    // region 0
    unsigned short* wp_q = wp + (size_t)8192 * 8;                 // region 1 (N=384)
    unsigned short* wp_o = wp + (size_t)20480 * 8;                // region 2 (N=256)
    float* qcat_ws = (float*)(wp + (size_t)28672 * 8);            // B*Q*384 fp32 = 11 MB
    float* samp_ws = qcat_ws + (size_t)BB * QQ * 384;             // B*Q*256 fp32 = 7.4 MB

    const int Mv = BB * SS;   // 156480
    const int Mq = BB * QQ;   // 7200

    // 0. pack all weights into bf16 MFMA fragment order
    pack_all<<<dim3(112), dim3(256), 0, stream>>>(W_v, W_off, W_attn, W_out, wp);
    // 1. value projection (bf16 MFMA, barrier-free)
    gemm_v_bf16<<<dim3((Mv + 127) / 128), dim3(256), 0, stream>>>(
        value, wp_v, b_v, v_bf, Mv);
    // 2. fused offsets+logits: qcat = query @ [W_off||W_attn] + [b_off||b_attn]
    gemm_q<<<dim3(6, (Mq + 63) / 64), dim3(256), 0, stream>>>(
        query, wp_q, b_off, b_attn, 256, nullptr, qcat_ws, Mq, 384);
    // 3. softmax + bilinear sampling + weighted sum
    msda_sample2<<<dim3(Mq / 2), dim3(256), 0, stream>>>(v_bf, qcat_ws, refp, samp_ws);
    // 4. output projection + residual
    gemm_q<<<dim3(4, (Mq + 63) / 64), dim3(256), 0, stream>>>(
        samp_ws, wp_o, b_out, b_out, 1 << 30, query, out, Mq, 256);
}